// Round 1
// baseline (567.887 us; speedup 1.0000x reference)
//
#include <hip/hip_runtime.h>
#include <math.h>
#include <float.h>

#define IN_DIM 256
#define OUT_DIM 512
#define MEM_LEN 131072
#define K_TOP 16

#define GEMV_BLOCKS 32
#define K_PER_BLOCK (IN_DIM / GEMV_BLOCKS)      // 8
#define DIST_BLOCKS 2048
#define ROWS_PER_BLOCK (MEM_LEN / DIST_BLOCKS)  // 64
#define CAND1_N (DIST_BLOCKS * K_TOP)           // 32768
#define LISTS_PER_THREAD (DIST_BLOCKS / 256)    // 8

__device__ __forceinline__ void ce(float& a, float& b) {
    float lo = fminf(a, b);
    float hi = fmaxf(a, b);
    a = lo; b = hi;
}

// Merge my sorted-16 with xor-partner lane's sorted-16, keep smallest 16
// sorted ascending (bitonic split + 4-stage merge). Both partners end with
// the identical merged list (min is symmetric). Exact.
__device__ __forceinline__ void merge_lanes(float v[16], int offset) {
    float w[16];
#pragma unroll
    for (int i = 0; i < 16; ++i) w[i] = __shfl_xor(v[i], offset, 64);
    float m[16];
#pragma unroll
    for (int i = 0; i < 16; ++i) m[i] = fminf(v[i], w[15 - i]);
#pragma unroll
    for (int d = 8; d >= 1; d >>= 1) {
#pragma unroll
        for (int i = 0; i < 16; ++i)
            if ((i & d) == 0) ce(m[i], m[i | d]);
    }
#pragma unroll
    for (int i = 0; i < 16; ++i) v[i] = m[i];
}

// In-register merge of two sorted-asc 16-lists, keep smallest 16 sorted asc.
__device__ __forceinline__ void merge16(float v[16], const float wv[16]) {
    float m[16];
#pragma unroll
    for (int i = 0; i < 16; ++i) m[i] = fminf(v[i], wv[15 - i]);
#pragma unroll
    for (int d = 8; d >= 1; d >>= 1) {
#pragma unroll
        for (int i = 0; i < 16; ++i)
            if ((i & d) == 0) ce(m[i], m[i | d]);
    }
#pragma unroll
    for (int i = 0; i < 16; ++i) v[i] = m[i];
}

// ---------------------------------------------------------------------------
// Kernel 1: split-K GEMV partials (atomic-free; bias folded into slice 0).
__global__ void gemv_partial_kernel(const float* __restrict__ data,
                                    const float* __restrict__ mean,
                                    const float* __restrict__ stdv,
                                    const float* __restrict__ W,
                                    const float* __restrict__ b,
                                    float* __restrict__ partial) {
    __shared__ float xn_s[K_PER_BLOCK];
    const int t = threadIdx.x;        // column 0..511
    const int g = blockIdx.x;         // K-slice
    if (t < K_PER_BLOCK) {
        int i = g * K_PER_BLOCK + t;
        float s = stdv[i];
        xn_s[t] = (s == 0.0f) ? 0.0f : (data[i] - mean[i]) / s;
    }
    __syncthreads();
    float acc = (g == 0) ? b[t] : 0.0f;
#pragma unroll
    for (int j = 0; j < K_PER_BLOCK; ++j)
        acc = fmaf(xn_s[j], W[(g * K_PER_BLOCK + j) * OUT_DIM + t], acc);
    partial[g * OUT_DIM + t] = acc;
}

// ---------------------------------------------------------------------------
// Kernel 2: finalize enc = tanh(sum of partials) ONCE (was redone per dist
// block: 2048 x 64KB L2 reads + 1M tanhf). Also zeroes the last-block flag
// (stream-ordered before kernel 3; kernel boundary flushes caches).
__global__ void enc_final_kernel(const float* __restrict__ partial,
                                 float* __restrict__ enc,
                                 unsigned int* __restrict__ flag) {
    const int t = threadIdx.x;        // 0..511
    float s = 0.0f;
#pragma unroll 8
    for (int g = 0; g < GEMV_BLOCKS; ++g) s += partial[g * OUT_DIM + t];
    enc[t] = tanhf(s);
    if (t == 0) *flag = 0u;
}

// ---------------------------------------------------------------------------
// Kernel 3: dist stream + per-block bitonic top-16 + last-block final merge.
// 2048 blocks x 256 threads (4 waves x 16 rows = 64 rows/block).
// Row sums: lane-local 8-elem partial per row held in s[0..15], then a
// row-packing butterfly tree (xor 32,16,8,4 + 2 cleanup butterflies) =
// 17 shuffles/wave vs 96 before. Pairing order identical to the old
// shfl_down chain -> bitwise-identical dists.
// Tail: last block (device-scope acq_rel atomic) merges the 2048 sorted
// 16-lists (pure merge networks, no sorts) and writes the weighted loss.
__global__ __launch_bounds__(256, 4)
void dist_topk_final_kernel(const float* __restrict__ enc,
                            const float* __restrict__ memory,
                            float* __restrict__ cand1,
                            unsigned int* __restrict__ flag,
                            const float* __restrict__ exp_w,
                            float* __restrict__ out) {
    __shared__ float bd[ROWS_PER_BLOCK];
    __shared__ float ws16[4][16];
    __shared__ unsigned int s_old;
    const int t = threadIdx.x;
    const int lane = t & 63;
    const int w = t >> 6;

    // enc broadcast: 2 KB, L2/L3-resident after first block touches it.
    const float4 e0 = *(const float4*)(enc + lane * 4);
    const float4 e1 = *(const float4*)(enc + 256 + lane * 4);

    const int base = blockIdx.x * ROWS_PER_BLOCK + w * 16;
    const float* mrow = memory + (size_t)base * OUT_DIM + lane * 4;
    float s[16];
#pragma unroll
    for (int r = 0; r < 16; ++r) {
        const float4 m0 = *(const float4*)(mrow);
        const float4 m1 = *(const float4*)(mrow + 256);
        s[r] = fabsf(m0.x - e0.x) + fabsf(m0.y - e0.y)
             + fabsf(m0.z - e0.z) + fabsf(m0.w - e0.w)
             + fabsf(m1.x - e1.x) + fabsf(m1.y - e1.y)
             + fabsf(m1.z - e1.z) + fabsf(m1.w - e1.w);
        mrow += OUT_DIM;
    }

    // Tree-reduce 16 rows x 64 lane-partials -> 16 row sums in 17 shuffles.
    // Stage A (xor 32): pack rows r / r+8 into lane halves.
    const bool lo32 = (lane < 32);
    float u[8];
#pragma unroll
    for (int r = 0; r < 8; ++r) {
        float a = lo32 ? s[r] : s[r + 8];
        float b = lo32 ? s[r + 8] : s[r];
        u[r] = a + __shfl_xor(b, 32, 64);
    }
    // Stage B (xor 16)
    const bool lo16 = ((lane & 16) == 0);
    float x4[4];
#pragma unroll
    for (int r = 0; r < 4; ++r) {
        float a = lo16 ? u[r] : u[r + 4];
        float b = lo16 ? u[r + 4] : u[r];
        x4[r] = a + __shfl_xor(b, 16, 64);
    }
    // Stage C (xor 8)
    const bool lo8 = ((lane & 8) == 0);
    float x2[2];
#pragma unroll
    for (int r = 0; r < 2; ++r) {
        float a = lo8 ? x4[r] : x4[r + 2];
        float b = lo8 ? x4[r + 2] : x4[r];
        x2[r] = a + __shfl_xor(b, 8, 64);
    }
    // Stage D (xor 4): row = (lane>>2) & 15 from here on.
    {
        const bool lo4 = ((lane & 4) == 0);
        float a = lo4 ? x2[0] : x2[1];
        float b = lo4 ? x2[1] : x2[0];
        float y = a + __shfl_xor(b, 4, 64);
        // Stage E: cleanup butterflies within each 4-lane group.
        y += __shfl_xor(y, 2, 64);
        y += __shfl_xor(y, 1, 64);
        if ((lane & 3) == 0) bd[w * 16 + (lane >> 2)] = y;
    }
    __syncthreads();

    // Wave 0: full bitonic sort of the 64 block dists, ascending; write top16.
    if (t < 64) {
        float v = bd[t];
#pragma unroll
        for (int k = 2; k <= 64; k <<= 1) {
#pragma unroll
            for (int j = k >> 1; j > 0; j >>= 1) {
                float pv = __shfl_xor(v, j, 64);
                bool up = ((t & k) == 0);
                bool takeMin = (((t & j) == 0) == up);
                v = takeMin ? fminf(v, pv) : fmaxf(v, pv);
            }
        }
        if (t < K_TOP) cand1[blockIdx.x * K_TOP + t] = v;
        if (t == 0) {
            // All cand1 writers are in THIS wave: the fence's wave-level
            // vmcnt drain + L2 writeback covers them (release). ACQ_REL
            // agent-scope atomic gives the last block its acquire.
            __threadfence();
            s_old = __hip_atomic_fetch_add(flag, 1u, __ATOMIC_ACQ_REL,
                                           __HIP_MEMORY_SCOPE_AGENT);
        }
    }
    __syncthreads();

    if (s_old == DIST_BLOCKS - 1) {
        // Last block: merge 2048 sorted 16-lists. 8 lists/thread.
        float v[16];
#pragma unroll
        for (int i = 0; i < 16; ++i) v[i] = cand1[t * K_TOP + i];
#pragma unroll
        for (int j = 1; j < LISTS_PER_THREAD; ++j) {
            float wv[16];
#pragma unroll
            for (int i = 0; i < 16; ++i)
                wv[i] = cand1[(t + j * 256) * K_TOP + i];
            merge16(v, wv);
        }
        merge_lanes(v, 1); merge_lanes(v, 2); merge_lanes(v, 4);
        merge_lanes(v, 8); merge_lanes(v, 16); merge_lanes(v, 32);
        if (lane == 0) {
#pragma unroll
            for (int i = 0; i < 16; ++i) ws16[w][i] = v[i];
        }
        __syncthreads();
        if (t < 64) {
            float uu[16];
#pragma unroll
            for (int i = 0; i < 16; ++i)
                uu[i] = (lane < 4) ? ws16[lane & 3][i] : FLT_MAX;
            merge_lanes(uu, 1);
            merge_lanes(uu, 2);
            if (lane == 0) {
                float num = 0.0f, den = 0.0f;
#pragma unroll
                for (int k = 0; k < K_TOP; ++k) {
                    float wk = exp_w[k];
                    num = fmaf(uu[k], wk, num);
                    den += wk;
                }
                out[0] = num / den;
            }
        }
    }
}

extern "C" void kernel_launch(void* const* d_in, const int* in_sizes, int n_in,
                              void* d_out, int out_size, void* d_ws, size_t ws_size,
                              hipStream_t stream) {
    const float* data   = (const float*)d_in[0];
    const float* mean   = (const float*)d_in[1];
    const float* stdv   = (const float*)d_in[2];
    const float* memory = (const float*)d_in[3];
    const float* W      = (const float*)d_in[4];
    const float* b      = (const float*)d_in[5];
    const float* exp_w  = (const float*)d_in[6];
    float* out = (float*)d_out;

    float* partial = (float*)d_ws;                       // 32*512 floats
    float* enc     = partial + GEMV_BLOCKS * OUT_DIM;    // 512 floats
    float* cand1   = enc + OUT_DIM;                      // 32768 floats
    unsigned int* flag = (unsigned int*)(cand1 + CAND1_N);

    gemv_partial_kernel<<<GEMV_BLOCKS, OUT_DIM, 0, stream>>>(data, mean, stdv, W, b, partial);
    enc_final_kernel<<<1, OUT_DIM, 0, stream>>>(partial, enc, flag);
    dist_topk_final_kernel<<<DIST_BLOCKS, 256, 0, stream>>>(enc, memory, cand1, flag, exp_w, out);
}

// Round 3
// 378.450 us; speedup vs baseline: 1.5006x; 1.5006x over previous
//
#include <hip/hip_runtime.h>
#include <math.h>
#include <float.h>

#define IN_DIM 256
#define OUT_DIM 512
#define MEM_LEN 131072
#define K_TOP 16

#define GEMV_BLOCKS 32
#define K_PER_BLOCK (IN_DIM / GEMV_BLOCKS)      // 8
#define DIST_BLOCKS 2048
#define ROWS_PER_BLOCK (MEM_LEN / DIST_BLOCKS)  // 64
#define CAND1_N (DIST_BLOCKS * K_TOP)           // 32768
#define LISTS_PER_THREAD (DIST_BLOCKS / 256)    // 8

__device__ __forceinline__ void ce(float& a, float& b) {
    float lo = fminf(a, b);
    float hi = fmaxf(a, b);
    a = lo; b = hi;
}

// Merge my sorted-16 with xor-partner lane's sorted-16, keep smallest 16
// sorted ascending (bitonic split + 4-stage merge). Both partners end with
// the identical merged list (min is symmetric). Exact.
__device__ __forceinline__ void merge_lanes(float v[16], int offset) {
    float w[16];
#pragma unroll
    for (int i = 0; i < 16; ++i) w[i] = __shfl_xor(v[i], offset, 64);
    float m[16];
#pragma unroll
    for (int i = 0; i < 16; ++i) m[i] = fminf(v[i], w[15 - i]);
#pragma unroll
    for (int d = 8; d >= 1; d >>= 1) {
#pragma unroll
        for (int i = 0; i < 16; ++i)
            if ((i & d) == 0) ce(m[i], m[i | d]);
    }
#pragma unroll
    for (int i = 0; i < 16; ++i) v[i] = m[i];
}

// In-register merge of two sorted-asc 16-lists, keep smallest 16 sorted asc.
__device__ __forceinline__ void merge16(float v[16], const float wv[16]) {
    float m[16];
#pragma unroll
    for (int i = 0; i < 16; ++i) m[i] = fminf(v[i], wv[15 - i]);
#pragma unroll
    for (int d = 8; d >= 1; d >>= 1) {
#pragma unroll
        for (int i = 0; i < 16; ++i)
            if ((i & d) == 0) ce(m[i], m[i | d]);
    }
#pragma unroll
    for (int i = 0; i < 16; ++i) v[i] = m[i];
}

// ---------------------------------------------------------------------------
// Kernel 1: split-K GEMV partials (atomic-free; bias folded into slice 0).
__global__ void gemv_partial_kernel(const float* __restrict__ data,
                                    const float* __restrict__ mean,
                                    const float* __restrict__ stdv,
                                    const float* __restrict__ W,
                                    const float* __restrict__ b,
                                    float* __restrict__ partial) {
    __shared__ float xn_s[K_PER_BLOCK];
    const int t = threadIdx.x;        // column 0..511
    const int g = blockIdx.x;         // K-slice
    if (t < K_PER_BLOCK) {
        int i = g * K_PER_BLOCK + t;
        float s = stdv[i];
        xn_s[t] = (s == 0.0f) ? 0.0f : (data[i] - mean[i]) / s;
    }
    __syncthreads();
    float acc = (g == 0) ? b[t] : 0.0f;
#pragma unroll
    for (int j = 0; j < K_PER_BLOCK; ++j)
        acc = fmaf(xn_s[j], W[(g * K_PER_BLOCK + j) * OUT_DIM + t], acc);
    partial[g * OUT_DIM + t] = acc;
}

// ---------------------------------------------------------------------------
// Kernel 2: finalize enc = tanh(sum of partials) ONCE. Same summation order
// as the old in-dist reduction (g ascending) -> bitwise-identical enc.
// Saves 2048 x 64KB partial re-reads + 1M tanhf from the dist kernel.
__global__ void enc_final_kernel(const float* __restrict__ partial,
                                 float* __restrict__ enc) {
    const int t = threadIdx.x;        // 0..511
    float s = 0.0f;
#pragma unroll 8
    for (int g = 0; g < GEMV_BLOCKS; ++g) s += partial[g * OUT_DIM + t];
    enc[t] = tanhf(s);
}

// ---------------------------------------------------------------------------
// Kernel 3: dist stream + per-block bitonic top-16 (round-0 proven hot loop:
// unroll 2, immediate per-row shfl_down reduce; NO fences/atomics).
// 2048 blocks x 256 threads (4 waves x 16 rows = 64 rows/block).
__global__ __launch_bounds__(256)
void dist_topk_kernel(const float* __restrict__ enc,
                      const float* __restrict__ memory,
                      float* __restrict__ cand1) {
    __shared__ float bd[ROWS_PER_BLOCK];
    const int t = threadIdx.x;
    const int lane = t & 63;
    const int w = t >> 6;

    // enc broadcast: 2 KB, L2-resident after first touch.
    const float4 e0 = *(const float4*)(enc + lane * 4);
    const float4 e1 = *(const float4*)(enc + 256 + lane * 4);

    const int base = blockIdx.x * ROWS_PER_BLOCK + w * 16;
    const float* mrow = memory + (size_t)base * OUT_DIM;
#pragma unroll 2
    for (int r = 0; r < 16; ++r) {
        const float4 m0 = *(const float4*)(mrow + lane * 4);
        const float4 m1 = *(const float4*)(mrow + 256 + lane * 4);
        float s = fabsf(m0.x - e0.x) + fabsf(m0.y - e0.y)
                + fabsf(m0.z - e0.z) + fabsf(m0.w - e0.w)
                + fabsf(m1.x - e1.x) + fabsf(m1.y - e1.y)
                + fabsf(m1.z - e1.z) + fabsf(m1.w - e1.w);
#pragma unroll
        for (int off = 32; off > 0; off >>= 1)
            s += __shfl_down(s, off, 64);
        if (lane == 0) bd[w * 16 + r] = s;
        mrow += OUT_DIM;
    }
    __syncthreads();

    // Wave 0: full bitonic sort of 64 values across lanes, ascending.
    if (t < 64) {
        float v = bd[t];
#pragma unroll
        for (int k = 2; k <= 64; k <<= 1) {
#pragma unroll
            for (int j = k >> 1; j > 0; j >>= 1) {
                float pv = __shfl_xor(v, j, 64);
                bool up = ((t & k) == 0);
                bool takeMin = (((t & j) == 0) == up);
                v = takeMin ? fminf(v, pv) : fmaxf(v, pv);
            }
        }
        if (t < K_TOP) cand1[blockIdx.x * K_TOP + t] = v;
    }
}

// ---------------------------------------------------------------------------
// Kernel 4: single-block merge of all 2048 sorted 16-lists + weighted loss.
// (Stream-ordered after kernel 3 -> no fences needed.) 256 threads:
// each merges 8 lists in-register, then 6 cross-lane merges per wave,
// then LDS merge of the 4 wave lists -> loss.
__global__ __launch_bounds__(256)
void select_final_kernel(const float* __restrict__ cand1,
                         const float* __restrict__ exp_w,
                         float* __restrict__ out) {
    __shared__ float ws16[4][16];
    const int t = threadIdx.x;
    const int lane = t & 63;
    const int w = t >> 6;

    float v[16];
#pragma unroll
    for (int i = 0; i < 16; ++i) v[i] = cand1[t * K_TOP + i];
#pragma unroll
    for (int j = 1; j < LISTS_PER_THREAD; ++j) {
        float wv[16];
#pragma unroll
        for (int i = 0; i < 16; ++i)
            wv[i] = cand1[(t + j * 256) * K_TOP + i];
        merge16(v, wv);
    }
    merge_lanes(v, 1); merge_lanes(v, 2); merge_lanes(v, 4);
    merge_lanes(v, 8); merge_lanes(v, 16); merge_lanes(v, 32);
    if (lane == 0) {
#pragma unroll
        for (int i = 0; i < 16; ++i) ws16[w][i] = v[i];
    }
    __syncthreads();

    if (t < 64) {
        float u[16];
#pragma unroll
        for (int i = 0; i < 16; ++i)
            u[i] = (lane < 4) ? ws16[lane & 3][i] : FLT_MAX;
        merge_lanes(u, 1);
        merge_lanes(u, 2);
        if (lane == 0) {
            float num = 0.0f, den = 0.0f;
#pragma unroll
            for (int k = 0; k < K_TOP; ++k) {
                float wk = exp_w[k];
                num = fmaf(u[k], wk, num);
                den += wk;
            }
            out[0] = num / den;
        }
    }
}

extern "C" void kernel_launch(void* const* d_in, const int* in_sizes, int n_in,
                              void* d_out, int out_size, void* d_ws, size_t ws_size,
                              hipStream_t stream) {
    const float* data   = (const float*)d_in[0];
    const float* mean   = (const float*)d_in[1];
    const float* stdv   = (const float*)d_in[2];
    const float* memory = (const float*)d_in[3];
    const float* W      = (const float*)d_in[4];
    const float* b      = (const float*)d_in[5];
    const float* exp_w  = (const float*)d_in[6];
    float* out = (float*)d_out;

    float* partial = (float*)d_ws;                       // 32*512 floats
    float* enc     = partial + GEMV_BLOCKS * OUT_DIM;    // 512 floats
    float* cand1   = enc + OUT_DIM;                      // 32768 floats

    gemv_partial_kernel<<<GEMV_BLOCKS, OUT_DIM, 0, stream>>>(data, mean, stdv, W, b, partial);
    enc_final_kernel<<<1, OUT_DIM, 0, stream>>>(partial, enc);
    dist_topk_kernel<<<DIST_BLOCKS, 256, 0, stream>>>(enc, memory, cand1);
    select_final_kernel<<<1, 256, 0, stream>>>(cand1, exp_w, out);
}